// Round 13
// baseline (206.734 us; speedup 1.0000x reference)
//
#include <hip/hip_runtime.h>
#include <hip/hip_bf16.h>

// ---------------------------------------------------------------------------
// MPS contraction, N=512 sites, D_PHY=4, D_BOND=128, VOC=1024.
// Faithful computation with EXACT all-zero early exit (state underflows to
// exact 0 after ~15 sites; site map is linear, so remaining sites stay 0).
// Round-13:
//  * __launch_bounds__(576,2): r12's (576,3) itself capped VGPR at 84
//    (256/3) — with 1 wg/CU (9 waves) the 3-wave/EU request bought nothing.
//    (,2) -> 128 VGPR cap at identical real occupancy.
//  * U-step restored to ONE 16x dwordx4 asm block (one MALL RTT, was 2).
//  * C-step hoisted BEFORE the site barrier (Clds double-buffered): C(t+1)
//    depends only on locally-committed Bpre/MtLds, so it computes during
//    barrier skew; post-barrier path starts directly at the U-step.
//  * prep: single batched n=10 Gram reduction (2 syncs, was 6).
// ---------------------------------------------------------------------------

__device__ __forceinline__ float2 cfma(float2 a, float2 b, float2 acc) {
    acc.x = fmaf(a.x, b.x, fmaf(-a.y, b.y, acc.x));
    acc.y = fmaf(a.x, b.y, fmaf( a.y, b.x, acc.y));
    return acc;
}
__device__ __forceinline__ float2 cfmac(float2 a, float2 b, float2 acc) {
    // acc + conj(a)*b
    acc.x = fmaf(a.x, b.x, fmaf( a.y, b.y, acc.x));
    acc.y = fmaf(a.x, b.y, fmaf(-a.y, b.x, acc.y));
    return acc;
}

// coherent (cache-bypassing) 8-byte load/store for the S exchange
__device__ __forceinline__ float2 ld_coh(const float2* p) {
    union { unsigned long long u; float2 f; } cv;
    cv.u = __hip_atomic_load((const unsigned long long*)p,
                             __ATOMIC_RELAXED, __HIP_MEMORY_SCOPE_AGENT);
    return cv.f;
}
__device__ __forceinline__ void st_coh(float2* p, float2 x) {
    union { unsigned long long u; float2 f; } cv;
    cv.f = x;
    __hip_atomic_store((unsigned long long*)p, cv.u,
                       __ATOMIC_RELAXED, __HIP_MEMORY_SCOPE_AGENT);
}

__device__ __forceinline__ double2 d2mul(double2 a, double2 b) {
    return make_double2(a.x*b.x - a.y*b.y, a.x*b.y + a.y*b.x);
}
__device__ __forceinline__ double2 d2conj(double2 a) { return make_double2(a.x, -a.y); }
__device__ __forceinline__ double2 d2add(double2 a, double2 b) {
    return make_double2(a.x + b.x, a.y + b.y);
}
__device__ __forceinline__ double2 d2sub(double2 a, double2 b) {
    return make_double2(a.x - b.x, a.y - b.y);
}

// LDS-only barrier: does NOT drain vmcnt (raw s_barrier).
__device__ __forceinline__ void lds_barrier() {
    asm volatile("s_waitcnt lgkmcnt(0)" ::: "memory");
    __builtin_amdgcn_s_barrier();
    __builtin_amdgcn_sched_barrier(0);
}

// M entry m=(j,k) for token v: Y = A_v * W (4x4), M[j,k] = sum_i conj(Y[i,j])Y[i,k]
__device__ __forceinline__ float2 m_entry(const float* __restrict__ a_re,
                                          const float* __restrict__ a_im,
                                          int v, int m, const float2* Wl)
{
    const int j = m >> 2, k = m & 3;
    float2 Arow[4][4];
    #pragma unroll
    for (int i = 0; i < 4; ++i) {
        float4 re = *(const float4*)(a_re + v*16 + i*4);
        float4 im = *(const float4*)(a_im + v*16 + i*4);
        Arow[i][0] = make_float2(re.x, im.x);
        Arow[i][1] = make_float2(re.y, im.y);
        Arow[i][2] = make_float2(re.z, im.z);
        Arow[i][3] = make_float2(re.w, im.w);
    }
    float2 acc = make_float2(0.f, 0.f);
    #pragma unroll
    for (int i = 0; i < 4; ++i) {
        float2 yj = make_float2(0.f, 0.f), yk = yj;
        #pragma unroll
        for (int q = 0; q < 4; ++q) {
            yj = cfma(Arow[i][q], Wl[q*4 + j], yj);
            yk = cfma(Arow[i][q], Wl[q*4 + k], yk);
        }
        acc = cfmac(yj, yk, acc);
    }
    return acc;
}

// batched block reduction over 8 waves (512 thr): 10 double2 in one round
__device__ void redN10(double2* v, double2 (*redm)[10]) {
    for (int off = 32; off; off >>= 1) {
        #pragma unroll
        for (int d = 0; d < 10; ++d) {
            v[d].x += __shfl_down(v[d].x, off, 64);
            v[d].y += __shfl_down(v[d].y, off, 64);
        }
    }
    const int wid = threadIdx.x >> 6, lane = threadIdx.x & 63;
    __syncthreads();
    if (lane == 0)
        #pragma unroll
        for (int d = 0; d < 10; ++d) redm[wid][d] = v[d];
    __syncthreads();
    #pragma unroll
    for (int d = 0; d < 10; ++d) {
        double2 s = make_double2(0.0, 0.0);
        for (int w = 0; w < 8; ++w) { s.x += redm[w][d].x; s.y += redm[w][d].y; }
        v[d] = s;
    }
}

// ---------------------------------------------------------------------------
// prep_kernel (1 wg x 512): zero barrier words; Gram G = A^H A; thread 0
// runs the LAPACK diag-sign recurrence + Cholesky + R^-1, writes W = R^-1 D.
// ---------------------------------------------------------------------------
__global__ __launch_bounds__(512) void prep_kernel(const float* __restrict__ a_re,
                                                   const float* __restrict__ a_im,
                                                   float2* __restrict__ Wout,
                                                   unsigned int* __restrict__ cnt)
{
    const int t = threadIdx.x;
    cnt[t] = 0u;
    __shared__ double2 redm[8][10];

    double2 gp[10];
    #pragma unroll
    for (int e = 0; e < 10; ++e) gp[e] = make_double2(0.0, 0.0);
    for (int rr = 0; rr < 8; ++rr) {
        const int r = t * 8 + rr;
        float4 fre = *(const float4*)(a_re + r*4);
        float4 fim = *(const float4*)(a_im + r*4);
        double r0 = fre.x, r1 = fre.y, r2 = fre.z, r3 = fre.w;
        double i0 = fim.x, i1 = fim.y, i2 = fim.z, i3 = fim.w;
#define GACC(e, rj, ij, rk, ik) \
        gp[e].x += rj*rk + ij*ik; gp[e].y += rj*ik - ij*rk;
        GACC(0, r0, i0, r0, i0)  GACC(1, r0, i0, r1, i1)
        GACC(2, r0, i0, r2, i2)  GACC(3, r0, i0, r3, i3)
        GACC(4, r1, i1, r1, i1)  GACC(5, r1, i1, r2, i2)
        GACC(6, r1, i1, r3, i3)  GACC(7, r2, i2, r2, i2)
        GACC(8, r2, i2, r3, i3)  GACC(9, r3, i3, r3, i3)
#undef GACC
    }
    redN10(gp, redm);

    if (t != 0) return;

    double2 G4[4][4];
    G4[0][0]=gp[0]; G4[0][1]=gp[1]; G4[0][2]=gp[2]; G4[0][3]=gp[3];
    G4[1][1]=gp[4]; G4[1][2]=gp[5]; G4[1][3]=gp[6];
    G4[2][2]=gp[7]; G4[2][3]=gp[8]; G4[3][3]=gp[9];
    G4[1][0]=d2conj(gp[1]); G4[2][0]=d2conj(gp[2]); G4[3][0]=d2conj(gp[3]);
    G4[2][1]=d2conj(gp[5]); G4[3][1]=d2conj(gp[6]); G4[3][2]=d2conj(gp[8]);
    G4[0][0].y=0.0; G4[1][1].y=0.0; G4[2][2].y=0.0; G4[3][3].y=0.0;

    // LAPACK diag-sign recurrence (Householder on G + top rows of A)
    double2 T[4][4];
    #pragma unroll
    for (int i = 0; i < 4; ++i)
        #pragma unroll
        for (int j = 0; j < 4; ++j)
            T[i][j] = make_double2((double)a_re[i*4+j], (double)a_im[i*4+j]);

    double dsgn[4];
    #pragma unroll
    for (int k = 0; k < 4; ++k) {
        double ssum = 0.0;
        #pragma unroll
        for (int i = 0; i < 4; ++i)
            if (i <= k) ssum += T[i][k].x*T[i][k].x + T[i][k].y*T[i][k].y;
        double xn = G4[k][k].x - ssum; if (xn < 0.0) xn = 0.0;
        double ar = T[k][k].x, ai = T[k][k].y;
        double nrm = sqrt(ar*ar + ai*ai + xn);
        double beta = (ar >= 0.0) ? -nrm : nrm;        // clarfg sign rule
        dsgn[k] = (beta >= 0.0) ? 1.0 : -1.0;
        double2 tau = make_double2((beta - ar)/beta, -ai/beta);
        double dr = ar - beta, di = ai;
        double dd = dr*dr + di*di;
        double2 s = make_double2(dr/dd, -di/dd);       // 1/(alpha-beta)
        double2 w[4];
        #pragma unroll
        for (int j = 0; j < 4; ++j) if (j > k) {
            double2 acc = G4[k][j];
            #pragma unroll
            for (int i = 0; i < 4; ++i)
                if (i <= k) acc = d2sub(acc, d2mul(d2conj(T[i][k]), T[i][j]));
            w[j] = d2add(T[k][j], d2mul(d2conj(s), acc));
        }
        #pragma unroll
        for (int j = 0; j < 4; ++j) if (j > k) {
            double2 tw = d2mul(tau, w[j]);
            T[k][j] = d2sub(T[k][j], tw);
            #pragma unroll
            for (int i = 0; i < 4; ++i)
                if (i > k) T[i][j] = d2sub(T[i][j], d2mul(tw, d2mul(s, T[i][k])));
        }
        T[k][k] = make_double2(beta, 0.0);
        #pragma unroll
        for (int i = 0; i < 4; ++i)
            if (i > k) T[i][k] = make_double2(0.0, 0.0);
    }

    // Cholesky (upper R): G = R^H R
    double2 R[4][4];
    #pragma unroll
    for (int k = 0; k < 4; ++k) {
        double dk = G4[k][k].x;
        #pragma unroll
        for (int i = 0; i < 4; ++i)
            if (i < k) dk -= R[i][k].x*R[i][k].x + R[i][k].y*R[i][k].y;
        if (dk < 1e-30) dk = 1e-30;
        double rkk = sqrt(dk);
        R[k][k] = make_double2(rkk, 0.0);
        #pragma unroll
        for (int j = 0; j < 4; ++j) if (j > k) {
            double2 acc = G4[k][j];
            #pragma unroll
            for (int i = 0; i < 4; ++i)
                if (i < k) acc = d2sub(acc, d2mul(d2conj(R[i][k]), R[i][j]));
            R[k][j] = make_double2(acc.x/rkk, acc.y/rkk);
        }
    }
    // X = R^-1 (upper triangular back-substitution)
    double2 X[4][4];
    #pragma unroll
    for (int j = 0; j < 4; ++j) {
        #pragma unroll
        for (int i = 0; i < 4; ++i) X[i][j] = make_double2(0.0, 0.0);
        X[j][j] = make_double2(1.0 / R[j][j].x, 0.0);
        #pragma unroll
        for (int ii = 0; ii < 3; ++ii) {
            const int i = j - 1 - ii;
            if (i >= 0) {
                double2 acc = make_double2(0.0, 0.0);
                #pragma unroll
                for (int m2 = 0; m2 < 4; ++m2)
                    if (m2 > i && m2 <= j) acc = d2add(acc, d2mul(R[i][m2], X[m2][j]));
                X[i][j] = make_double2(-acc.x / R[i][i].x, -acc.y / R[i][i].x);
            }
        }
    }
    #pragma unroll
    for (int q = 0; q < 4; ++q)
        #pragma unroll
        for (int j = 0; j < 4; ++j)
            Wout[q*4 + j] = make_float2((float)(X[q][j].x * dsgn[j]),
                                        (float)(X[q][j].y * dsgn[j]));
}

// ---------------------------------------------------------------------------
// Flat grid barrier + liveness, SELECTIVE drain: only waves holding S stores
// (tid<128) wait vmcnt(0); everyone drains lgkm. Other waves' in-flight cold
// loads legitimately span the barrier.
// ---------------------------------------------------------------------------
#define NWG 128u
__device__ __forceinline__ bool site_barrier(unsigned int* addr,
                                             unsigned* nzw, int* live_lds, int tid)
{
    asm volatile("s_waitcnt lgkmcnt(0)" ::: "memory");
    if (tid < 128) asm volatile("s_waitcnt vmcnt(0)" ::: "memory"); // S stores acked
    __builtin_amdgcn_s_barrier();
    __builtin_amdgcn_sched_barrier(0);
    if (tid == 0) {
        unsigned add = 1u | ((nzw[0] | nzw[1]) ? 0x10000u : 0u);
        __hip_atomic_fetch_add(addr, add, __ATOMIC_RELAXED, __HIP_MEMORY_SCOPE_AGENT);
        unsigned v;
        for (;;) {
            v = __hip_atomic_load(addr, __ATOMIC_RELAXED, __HIP_MEMORY_SCOPE_AGENT);
            if ((v & 0xffffu) >= NWG) break;
            __builtin_amdgcn_s_sleep(1);
        }
        *live_lds = (int)(v >> 16);
    }
    asm volatile("s_waitcnt lgkmcnt(0)" ::: "memory");
    __builtin_amdgcn_s_barrier();
    __builtin_amdgcn_sched_barrier(0);
    return *live_lds != 0;
}

// ---------------------------------------------------------------------------
// The one cooperative kernel. 128 wgs x 576 threads (8 compute waves + 1
// prefetch wave); wg owns output column c (XCD-grouped mapping).
// ---------------------------------------------------------------------------
__global__ __launch_bounds__(576, 2) void scan_kernel(
    const float* __restrict__ a_re,  const float* __restrict__ a_im,
    const float* __restrict__ b0_re, const float* __restrict__ b0_im,
    const float* __restrict__ bm_re, const float* __restrict__ bm_im,
    const float* __restrict__ bl_re, const float* __restrict__ bl_im,
    const int*  __restrict__ tokens, const float2* __restrict__ Wglob,
    float2* SbufA, float2* SbufB,
    unsigned int* cnt, float* out, int out_size)
{
    const int tid = threadIdx.x;
    const int bid = blockIdx.x;
    const int c   = ((bid & 7) << 4) | (bid >> 3);   // same-XCD wgs -> adjacent c
    const int i16 = bid >> 3;                        // slice index within group

    __shared__ float2 Clds[2][4][128];     //  8 KB (double-buffered C)
    __shared__ float4 Upart4[8][256];      // 32 KB
    __shared__ float4 U4[256];             //  4 KB
    __shared__ float4 P16_4[16][64];       // 16 KB
    __shared__ float2 Bpre[2][4][128];     //  8 KB
    __shared__ float2 fred[16];
    __shared__ float2 Wlds[16];
    __shared__ float2 MtLds[2][16];
    __shared__ unsigned nzw[2];
    __shared__ int live_lds;

    const int a = tid & 127;
    const int h = tid >> 7;

    float2* Sread = SbufA;
    float2* Swrite = SbufB;
    bool dead = false;
    float warmacc = 0.f;
    float wm0 = 0.f, wm1 = 0.f, wm2 = 0.f, wm3 = 0.f;  // loop-carried warm

    // ---- prologue warm: FULL tiles 0 and 1, per-group slice i16 (32 KB/wg)
    if (tid < 512) {
        const float4* t0r = (const float4*)bm_re + i16*1024;
        const float4* t0i = (const float4*)bm_im + i16*1024;
        #pragma unroll
        for (int k = 0; k < 2; ++k) {
            float4 x0 = t0r[tid + k*512],          y0 = t0i[tid + k*512];
            float4 x1 = t0r[16384 + tid + k*512],  y1 = t0i[16384 + tid + k*512];
            warmacc += x0.x+x0.y+x0.z+x0.w + y0.x+y0.y+y0.z+y0.w
                     + x1.x+x1.y+x1.z+x1.w + y1.x+y1.y+y1.z+y1.w;
        }
    }

    // ---- W from prep_kernel (tiny, L3-hot)
    if (tid < 16) Wlds[tid] = Wglob[tid];
    __syncthreads();

    // ---- M_0, M_1 and Bpre[1] (site 1 C-operands, tile 0)
    if (tid < 32) {
        const int which = tid >> 4, m = tid & 15;
        MtLds[which][m] = m_entry(a_re, a_im, tokens[which], m, Wlds);
    }
    if (tid < 512) {
        Bpre[1][h][a] = make_float2(bm_re[(h*128 + a)*128 + c],
                                    bm_im[(h*128 + a)*128 + c]);
    }
    __syncthreads();

    // ---- site 0 (tid<128) + C-step for site 1 (tid<512), both pre-barrier
    if (tid < 512) {
        float2 acc = make_float2(0.f, 0.f);
        #pragma unroll
        for (int q = 0; q < 4; ++q)
            acc = cfma(MtLds[1][h*4 + q], Bpre[1][q][a], acc);
        Clds[1][h][a] = acc;
    }
    if (tid < 128) {
        const int r = a;
        float2 brr[4], bcc[4];
        for (int p = 0; p < 4; ++p) {
            brr[p] = make_float2(b0_re[p*128 + r], b0_im[p*128 + r]);
            bcc[p] = make_float2(b0_re[p*128 + c], b0_im[p*128 + c]);
        }
        float2 acc = make_float2(0.f, 0.f);
        for (int p = 0; p < 4; ++p) {
            float2 tp = make_float2(0.f, 0.f);
            for (int q = 0; q < 4; ++q) tp = cfma(MtLds[0][p*4 + q], bcc[q], tp);
            acc = cfmac(brr[p], tp, acc);
        }
        st_coh(&SbufA[c*128 + r], acc);
        int nz = (acc.x != 0.f) || (acc.y != 0.f);
        unsigned long long m = __ballot(nz);
        if ((tid & 63) == 0) nzw[tid >> 6] = (m != 0ULL) ? 1u : 0u;
    }

    if (!site_barrier(&cnt[0], nzw, &live_lds, tid)) dead = true;

    if (!dead) {
        for (int t = 1; t <= 510; ++t) {
            const int cur = t & 1, nxt = cur ^ 1;
            const float* br = bm_re + (size_t)(t - 1) * 65536;
            const float* bi = bm_im + (size_t)(t - 1) * 65536;

            // ============ prefetch wave: gather + M + warm-touch ==========
            float2 bp[8];
            float2 macc = make_float2(0.f, 0.f);
            int j = 0;
            if (tid >= 512) {
                j = tid - 512;                         // 0..63
                // consume LAST site's warm touches (had a full site of slack)
                warmacc += wm0 + wm1 + wm2 + wm3;
                // (a) Bpre gather for site t+1 from tile t (L2-warm)
                if (t < 510) {
                    const float* br2 = bm_re + (size_t)t * 65536;
                    const float* bi2 = bm_im + (size_t)t * 65536;
                    #pragma unroll
                    for (int e = 0; e < 8; ++e) {
                        const int idx = j + e*64, q = idx >> 7, a2i = idx & 127;
                        bp[e] = make_float2(br2[(q*128 + a2i)*128 + c],
                                            bi2[(q*128 + a2i)*128 + c]);
                    }
                }
                // (b) M_{t+1} (L2-hot A table)
                if (j < 16) macc = m_entry(a_re, a_im, tokens[t+1], j, Wlds);
                // (c) line-touch warm of tile t+1, slice i16 (1 ld / 128B line)
                if (t < 509) {
                    const float* wr = bm_re + (size_t)(t+1)*65536 + i16*4096;
                    const float* wi = bm_im + (size_t)(t+1)*65536 + i16*4096;
                    wm0 = wr[j*32];  wm1 = wr[2048 + j*32];
                    wm2 = wi[j*32];  wm3 = wi[2048 + j*32];
                } else { wm0 = wm1 = wm2 = wm3 = 0.f; }
            }

            // ================= compute waves (tid < 512) ==================
            // ---- U-step (C was computed pre-barrier): thread sub=tid>>6,
            //      a2=tid&63; ONE asm block: 16 dwordx4 bypass loads.
            if (tid < 512) {
                const int sub = tid >> 6, a2 = tid & 63;
                const float2 (*CB)[128] = Clds[cur];
                float2 u00 = make_float2(0,0), u01 = u00, u02 = u00, u03 = u00;
                float2 u10 = u00, u11 = u00, u12 = u00, u13 = u00;
                {
                    const float2* _b0 = Sread + (sub*16)*128 + 2*a2;
                    const float2* _b1 = _b0 + 512;
                    const float2* _b2 = _b0 + 1024;
                    const float2* _b3 = _b0 + 1536;
                    float4 t0,t1,t2,t3,t4,t5,t6,t7,t8,t9,t10,t11,t12,t13,t14,t15;
                    asm volatile(
                      "global_load_dwordx4 %0, %16, off sc0 sc1\n\t"
                      "global_load_dwordx4 %1, %16, off offset:1024 sc0 sc1\n\t"
                      "global_load_dwordx4 %2, %16, off offset:2048 sc0 sc1\n\t"
                      "global_load_dwordx4 %3, %16, off offset:3072 sc0 sc1\n\t"
                      "global_load_dwordx4 %4, %17, off sc0 sc1\n\t"
                      "global_load_dwordx4 %5, %17, off offset:1024 sc0 sc1\n\t"
                      "global_load_dwordx4 %6, %17, off offset:2048 sc0 sc1\n\t"
                      "global_load_dwordx4 %7, %17, off offset:3072 sc0 sc1\n\t"
                      "global_load_dwordx4 %8, %18, off sc0 sc1\n\t"
                      "global_load_dwordx4 %9, %18, off offset:1024 sc0 sc1\n\t"
                      "global_load_dwordx4 %10, %18, off offset:2048 sc0 sc1\n\t"
                      "global_load_dwordx4 %11, %18, off offset:3072 sc0 sc1\n\t"
                      "global_load_dwordx4 %12, %19, off sc0 sc1\n\t"
                      "global_load_dwordx4 %13, %19, off offset:1024 sc0 sc1\n\t"
                      "global_load_dwordx4 %14, %19, off offset:2048 sc0 sc1\n\t"
                      "global_load_dwordx4 %15, %19, off offset:3072 sc0 sc1\n\t"
                      "s_waitcnt vmcnt(0)"
                      : "=&v"(t0), "=&v"(t1), "=&v"(t2), "=&v"(t3),
                        "=&v"(t4), "=&v"(t5), "=&v"(t6), "=&v"(t7),
                        "=&v"(t8), "=&v"(t9), "=&v"(t10), "=&v"(t11),
                        "=&v"(t12), "=&v"(t13), "=&v"(t14), "=&v"(t15)
                      : "v"(_b0), "v"(_b1), "v"(_b2), "v"(_b3));
                    float4 tt[16] = {t0,t1,t2,t3,t4,t5,t6,t7,
                                     t8,t9,t10,t11,t12,t13,t14,t15};
                    #pragma unroll
                    for (int e = 0; e < 16; ++e) {
                        const int b = sub*16 + e;
                        float2 slo = make_float2(tt[e].x, tt[e].y);
                        float2 shi = make_float2(tt[e].z, tt[e].w);
                        float2 c0 = CB[0][b], c1 = CB[1][b];
                        float2 c2 = CB[2][b], c3 = CB[3][b];
                        u00 = cfma(slo, c0, u00);  u10 = cfma(shi, c0, u10);
                        u01 = cfma(slo, c1, u01);  u11 = cfma(shi, c1, u11);
                        u02 = cfma(slo, c2, u02);  u12 = cfma(shi, c2, u12);
                        u03 = cfma(slo, c3, u03);  u13 = cfma(shi, c3, u13);
                    }
                }
                Upart4[sub][0*64 + a2] = make_float4(u00.x,u00.y,u10.x,u10.y);
                Upart4[sub][1*64 + a2] = make_float4(u01.x,u01.y,u11.x,u11.y);
                Upart4[sub][2*64 + a2] = make_float4(u02.x,u02.y,u12.x,u12.y);
                Upart4[sub][3*64 + a2] = make_float4(u03.x,u03.y,u13.x,u13.y);
            }
            lds_barrier();
            if (tid < 256) {
                float4 s = Upart4[0][tid];
                #pragma unroll
                for (int w = 1; w < 8; ++w) {
                    float4 x = Upart4[w][tid];
                    s.x += x.x; s.y += x.y; s.z += x.z; s.w += x.w;
                }
                U4[tid] = s;
            }
            lds_barrier();

            // ---- out-step: thread pg=tid>>5 (pa-block), r4=tid&31 (r-quad);
            //      float4 loads (L2-hit after warm), unroll pairs.
            if (tid < 512) {
                const int pg = tid >> 5, r4 = tid & 31;
                const int p = pg >> 2, abase = (pg & 3) * 32;
                const int pabase = pg * 32;
                const float4* br4 = (const float4*)br;
                const float4* bi4 = (const float4*)bi;
                float2 o0 = make_float2(0,0), o1 = o0, o2 = o0, o3 = o0;
                #pragma unroll 4
                for (int k = 0; k < 32; k += 2) {
                    float4 u2 = U4[p*64 + ((abase + k) >> 1)];
                    float2 Ua = make_float2(u2.x, u2.y);
                    float2 Ub = make_float2(u2.z, u2.w);
                    float4 ra = br4[(pabase + k)*32 + r4];
                    float4 ia = bi4[(pabase + k)*32 + r4];
                    float4 rb = br4[(pabase + k + 1)*32 + r4];
                    float4 ib = bi4[(pabase + k + 1)*32 + r4];
                    o0 = cfmac(make_float2(ra.x, ia.x), Ua, o0);
                    o1 = cfmac(make_float2(ra.y, ia.y), Ua, o1);
                    o2 = cfmac(make_float2(ra.z, ia.z), Ua, o2);
                    o3 = cfmac(make_float2(ra.w, ia.w), Ua, o3);
                    o0 = cfmac(make_float2(rb.x, ib.x), Ub, o0);
                    o1 = cfmac(make_float2(rb.y, ib.y), Ub, o1);
                    o2 = cfmac(make_float2(rb.z, ib.z), Ub, o2);
                    o3 = cfmac(make_float2(rb.w, ib.w), Ub, o3);
                }
                // staggered: 16B/lane consecutive -> conflict-free
                P16_4[pg][r4]      = make_float4(o0.x,o0.y,o1.x,o1.y);
                P16_4[pg][32 + r4] = make_float4(o2.x,o2.y,o3.x,o3.y);
            }
            lds_barrier();
            if (tid < 128) {
                const int r = a;
                const int m = r & 3, q = r >> 2;
                const int pidx = (m < 2) ? (2*q + m) : (64 + 2*q + (m - 2));
                const float2* Prow = (const float2*)(&P16_4[0][0]);
                float2 fin = make_float2(0,0);
                #pragma unroll
                for (int w = 0; w < 16; ++w) {
                    float2 x = Prow[w*128 + pidx];
                    fin.x += x.x; fin.y += x.y;
                }
                st_coh(&Swrite[c * 128 + r], fin);          // write-through
                int nz = (fin.x != 0.f) || (fin.y != 0.f);
                unsigned long long m2 = __ballot(nz);
                if ((tid & 63) == 0) nzw[tid >> 6] = (m2 != 0ULL) ? 1u : 0u;
            }

            // ============ prefetch wave: COMMIT (bp oldest in FIFO) =======
            if (tid >= 512) {
                if (t < 510) {
                    #pragma unroll
                    for (int e = 0; e < 8; ++e) {
                        const int idx = j + e*64, q = idx >> 7, a2i = idx & 127;
                        Bpre[nxt][q][a2i] = bp[e];
                    }
                }
                if (j < 16) MtLds[nxt][j] = macc;
            }
            lds_barrier();

            // ---- C-step for site t+1, PRE-barrier (local data only)
            if (t < 510 && tid < 512) {
                float2 acc = make_float2(0.f, 0.f);
                #pragma unroll
                for (int q = 0; q < 4; ++q)
                    acc = cfma(MtLds[nxt][h*4 + q], Bpre[nxt][q][a], acc);
                Clds[nxt][h][a] = acc;
            }

            if (!site_barrier(&cnt[t], nzw, &live_lds, tid)) { dead = true; break; }
            float2* tmp = Sread; Sread = Swrite; Swrite = tmp;
        }
    }
    warmacc += wm0 + wm1 + wm2 + wm3;          // consume final warm touches

    if (out_size < 0) out[2] = warmacc;        // never true: keeps warm loads

    if (dead) {
        if (bid == 0 && tid == 0) {
            out[0] = 0.f;
            if (out_size > 1) out[1] = 0.f;
        }
        return;
    }
    if (bid != 0) return;

    // ---- final site: Bl (4,128,1), M_511 = MtLds[1]; Sread = S(510) transposed
    if (tid < 512) {   // t1[q=h][a] = sum_b S[a,b] * Bl[q,b]
        float2 acc = make_float2(0,0);
        for (int b = 0; b < 128; ++b) {
            float2 s = ld_coh(&Sread[b * 128 + a]);
            float2 bl = make_float2(bl_re[h*128 + b], bl_im[h*128 + b]);
            acc = cfma(s, bl, acc);
        }
        Clds[0][h][a] = acc;
    }
    __syncthreads();
    float2 tot = make_float2(0,0);
    if (tid < 512) {
        float2 tp = make_float2(0,0);
        for (int q = 0; q < 4; ++q) tp = cfma(MtLds[1][h*4 + q], Clds[0][q][a], tp);
        float2 blv = make_float2(bl_re[h*128 + a], bl_im[h*128 + a]);
        tot = cfmac(blv, tp, make_float2(0,0));
    }
    for (int off = 32; off; off >>= 1) {
        tot.x += __shfl_down(tot.x, off, 64);
        tot.y += __shfl_down(tot.y, off, 64);
    }
    if ((tid & 63) == 0) fred[tid >> 6] = tot;
    __syncthreads();
    if (tid == 0) {
        float2 s = make_float2(0,0);
        for (int w = 0; w < 9; ++w) { s.x += fred[w].x; s.y += fred[w].y; }
        out[0] = s.x;
        if (out_size > 1) out[1] = s.y;
    }
}

// ---------------------------------------------------------------------------
extern "C" void kernel_launch(void* const* d_in, const int* in_sizes, int n_in,
                              void* d_out, int out_size, void* d_ws, size_t ws_size,
                              hipStream_t stream)
{
    const float* a_re  = (const float*)d_in[0];
    const float* a_im  = (const float*)d_in[1];
    const float* b0_re = (const float*)d_in[2];
    const float* b0_im = (const float*)d_in[3];
    const float* bm_re = (const float*)d_in[4];
    const float* bm_im = (const float*)d_in[5];
    const float* bl_re = (const float*)d_in[6];
    const float* bl_im = (const float*)d_in[7];
    const int*  tokens = (const int*)d_in[8];

    char* ws = (char*)d_ws;
    float2* S0   = (float2*)(ws + 196608);            // 131072 B
    float2* S1b  = (float2*)(ws + 327680);            // 131072 B
    unsigned int* cnt = (unsigned int*)(ws + 458752); // 2048 B
    float2* W    = (float2*)(ws + 460800);            // 128 B

    prep_kernel<<<dim3(1), dim3(512), 0, stream>>>(a_re, a_im, W, cnt);

    float* outf = (float*)d_out;
    int osz = out_size;
    void* args[] = {
        (void*)&a_re, (void*)&a_im, (void*)&b0_re, (void*)&b0_im,
        (void*)&bm_re, (void*)&bm_im, (void*)&bl_re, (void*)&bl_im,
        (void*)&tokens, (void*)&W,
        (void*)&S0, (void*)&S1b, (void*)&cnt, (void*)&outf, (void*)&osz
    };
    hipLaunchCooperativeKernel((const void*)scan_kernel, dim3(128), dim3(576),
                               args, 0, stream);
}

// Round 14
// 195.911 us; speedup vs baseline: 1.0552x; 1.0552x over previous
//
#include <hip/hip_runtime.h>
#include <hip/hip_bf16.h>

// ---------------------------------------------------------------------------
// MPS contraction, N=512 sites, D_PHY=4, D_BOND=128, VOC=1024.
// Faithful computation with EXACT all-zero early exit (state underflows to
// exact 0 after ~15 sites; site map is linear, so remaining sites stay 0).
// Round-14: REVERT to the round-12 kernel (best measured: 199 us).
// r13's two changes both regressed: (576,2) did not lift the allocator's
// 84-VGPR choice, and the single 16-load asm block spilled (WRITE 3.1->4.9MB)
// while the C-hoist restructure cost net time (scan 170->183us).
// r12 structure: prep_kernel (1 wg; Gram + Cholesky + diag-sign -> W),
// cooperative scan of 128 wgs x 576 thr (8 compute waves + 1 prefetch wave),
// selective-drain flat grid barrier, write-through S exchange, full-tile
// L2 warm one site ahead, 2x8-load bypass U-step, float4 out-step.
// Per-site cost ~11us == serial-chain model (S-writeback -> rendezvous ->
// bypass RTT -> 4 phase stages + L2 stream): sync-latency floor for this
// decomposition, not a memory/compute roofline.
// ---------------------------------------------------------------------------

__device__ __forceinline__ float2 cfma(float2 a, float2 b, float2 acc) {
    acc.x = fmaf(a.x, b.x, fmaf(-a.y, b.y, acc.x));
    acc.y = fmaf(a.x, b.y, fmaf( a.y, b.x, acc.y));
    return acc;
}
__device__ __forceinline__ float2 cfmac(float2 a, float2 b, float2 acc) {
    // acc + conj(a)*b
    acc.x = fmaf(a.x, b.x, fmaf( a.y, b.y, acc.x));
    acc.y = fmaf(a.x, b.y, fmaf(-a.y, b.x, acc.y));
    return acc;
}

// coherent (cache-bypassing) 8-byte load/store for the S exchange
__device__ __forceinline__ float2 ld_coh(const float2* p) {
    union { unsigned long long u; float2 f; } cv;
    cv.u = __hip_atomic_load((const unsigned long long*)p,
                             __ATOMIC_RELAXED, __HIP_MEMORY_SCOPE_AGENT);
    return cv.f;
}
__device__ __forceinline__ void st_coh(float2* p, float2 x) {
    union { unsigned long long u; float2 f; } cv;
    cv.f = x;
    __hip_atomic_store((unsigned long long*)p, cv.u,
                       __ATOMIC_RELAXED, __HIP_MEMORY_SCOPE_AGENT);
}

__device__ __forceinline__ double2 d2mul(double2 a, double2 b) {
    return make_double2(a.x*b.x - a.y*b.y, a.x*b.y + a.y*b.x);
}
__device__ __forceinline__ double2 d2conj(double2 a) { return make_double2(a.x, -a.y); }
__device__ __forceinline__ double2 d2add(double2 a, double2 b) {
    return make_double2(a.x + b.x, a.y + b.y);
}
__device__ __forceinline__ double2 d2sub(double2 a, double2 b) {
    return make_double2(a.x - b.x, a.y - b.y);
}

// LDS-only barrier: does NOT drain vmcnt (raw s_barrier).
__device__ __forceinline__ void lds_barrier() {
    asm volatile("s_waitcnt lgkmcnt(0)" ::: "memory");
    __builtin_amdgcn_s_barrier();
    __builtin_amdgcn_sched_barrier(0);
}

// M entry m=(j,k) for token v: Y = A_v * W (4x4), M[j,k] = sum_i conj(Y[i,j])Y[i,k]
__device__ __forceinline__ float2 m_entry(const float* __restrict__ a_re,
                                          const float* __restrict__ a_im,
                                          int v, int m, const float2* Wl)
{
    const int j = m >> 2, k = m & 3;
    float2 Arow[4][4];
    #pragma unroll
    for (int i = 0; i < 4; ++i) {
        float4 re = *(const float4*)(a_re + v*16 + i*4);
        float4 im = *(const float4*)(a_im + v*16 + i*4);
        Arow[i][0] = make_float2(re.x, im.x);
        Arow[i][1] = make_float2(re.y, im.y);
        Arow[i][2] = make_float2(re.z, im.z);
        Arow[i][3] = make_float2(re.w, im.w);
    }
    float2 acc = make_float2(0.f, 0.f);
    #pragma unroll
    for (int i = 0; i < 4; ++i) {
        float2 yj = make_float2(0.f, 0.f), yk = yj;
        #pragma unroll
        for (int q = 0; q < 4; ++q) {
            yj = cfma(Arow[i][q], Wl[q*4 + j], yj);
            yk = cfma(Arow[i][q], Wl[q*4 + k], yk);
        }
        acc = cfmac(yj, yk, acc);
    }
    return acc;
}

// batched block reduction over 8 waves (512 thr)
__device__ void redN8(double2* v, int n, double2 (*redm)[4]) {
    for (int off = 32; off; off >>= 1) {
        for (int d = 0; d < n; ++d) {
            v[d].x += __shfl_down(v[d].x, off, 64);
            v[d].y += __shfl_down(v[d].y, off, 64);
        }
    }
    const int wid = threadIdx.x >> 6, lane = threadIdx.x & 63;
    __syncthreads();
    if (lane == 0)
        for (int d = 0; d < n; ++d) redm[wid][d] = v[d];
    __syncthreads();
    for (int d = 0; d < n; ++d) {
        double2 s = make_double2(0.0, 0.0);
        for (int w = 0; w < 8; ++w) { s.x += redm[w][d].x; s.y += redm[w][d].y; }
        v[d] = s;
    }
}

// ---------------------------------------------------------------------------
// prep_kernel (1 wg x 512): zero barrier words; Gram G = A^H A; thread 0
// runs the LAPACK diag-sign recurrence + Cholesky + R^-1, writes W = R^-1 D.
// Spill traffic: one thread's worth (negligible).
// ---------------------------------------------------------------------------
__global__ __launch_bounds__(512) void prep_kernel(const float* __restrict__ a_re,
                                                   const float* __restrict__ a_im,
                                                   float2* __restrict__ Wout,
                                                   unsigned int* __restrict__ cnt)
{
    const int t = threadIdx.x;
    cnt[t] = 0u;
    __shared__ double2 redm[8][4];

    double2 gp[10];
    #pragma unroll
    for (int e = 0; e < 10; ++e) gp[e] = make_double2(0.0, 0.0);
    for (int rr = 0; rr < 8; ++rr) {
        const int r = t * 8 + rr;
        float4 fre = *(const float4*)(a_re + r*4);
        float4 fim = *(const float4*)(a_im + r*4);
        double r0 = fre.x, r1 = fre.y, r2 = fre.z, r3 = fre.w;
        double i0 = fim.x, i1 = fim.y, i2 = fim.z, i3 = fim.w;
#define GACC(e, rj, ij, rk, ik) \
        gp[e].x += rj*rk + ij*ik; gp[e].y += rj*ik - ij*rk;
        GACC(0, r0, i0, r0, i0)  GACC(1, r0, i0, r1, i1)
        GACC(2, r0, i0, r2, i2)  GACC(3, r0, i0, r3, i3)
        GACC(4, r1, i1, r1, i1)  GACC(5, r1, i1, r2, i2)
        GACC(6, r1, i1, r3, i3)  GACC(7, r2, i2, r2, i2)
        GACC(8, r2, i2, r3, i3)  GACC(9, r3, i3, r3, i3)
#undef GACC
    }
    redN8(gp + 0, 4, redm);
    redN8(gp + 4, 4, redm);
    redN8(gp + 8, 2, redm);

    if (t != 0) return;

    double2 G4[4][4];
    G4[0][0]=gp[0]; G4[0][1]=gp[1]; G4[0][2]=gp[2]; G4[0][3]=gp[3];
    G4[1][1]=gp[4]; G4[1][2]=gp[5]; G4[1][3]=gp[6];
    G4[2][2]=gp[7]; G4[2][3]=gp[8]; G4[3][3]=gp[9];
    G4[1][0]=d2conj(gp[1]); G4[2][0]=d2conj(gp[2]); G4[3][0]=d2conj(gp[3]);
    G4[2][1]=d2conj(gp[5]); G4[3][1]=d2conj(gp[6]); G4[3][2]=d2conj(gp[8]);
    G4[0][0].y=0.0; G4[1][1].y=0.0; G4[2][2].y=0.0; G4[3][3].y=0.0;

    // LAPACK diag-sign recurrence (Householder on G + top rows of A)
    double2 T[4][4];
    #pragma unroll
    for (int i = 0; i < 4; ++i)
        #pragma unroll
        for (int j = 0; j < 4; ++j)
            T[i][j] = make_double2((double)a_re[i*4+j], (double)a_im[i*4+j]);

    double dsgn[4];
    #pragma unroll
    for (int k = 0; k < 4; ++k) {
        double ssum = 0.0;
        #pragma unroll
        for (int i = 0; i < 4; ++i)
            if (i <= k) ssum += T[i][k].x*T[i][k].x + T[i][k].y*T[i][k].y;
        double xn = G4[k][k].x - ssum; if (xn < 0.0) xn = 0.0;
        double ar = T[k][k].x, ai = T[k][k].y;
        double nrm = sqrt(ar*ar + ai*ai + xn);
        double beta = (ar >= 0.0) ? -nrm : nrm;        // clarfg sign rule
        dsgn[k] = (beta >= 0.0) ? 1.0 : -1.0;
        double2 tau = make_double2((beta - ar)/beta, -ai/beta);
        double dr = ar - beta, di = ai;
        double dd = dr*dr + di*di;
        double2 s = make_double2(dr/dd, -di/dd);       // 1/(alpha-beta)
        double2 w[4];
        #pragma unroll
        for (int j = 0; j < 4; ++j) if (j > k) {
            double2 acc = G4[k][j];
            #pragma unroll
            for (int i = 0; i < 4; ++i)
                if (i <= k) acc = d2sub(acc, d2mul(d2conj(T[i][k]), T[i][j]));
            w[j] = d2add(T[k][j], d2mul(d2conj(s), acc));
        }
        #pragma unroll
        for (int j = 0; j < 4; ++j) if (j > k) {
            double2 tw = d2mul(tau, w[j]);
            T[k][j] = d2sub(T[k][j], tw);
            #pragma unroll
            for (int i = 0; i < 4; ++i)
                if (i > k) T[i][j] = d2sub(T[i][j], d2mul(tw, d2mul(s, T[i][k])));
        }
        T[k][k] = make_double2(beta, 0.0);
        #pragma unroll
        for (int i = 0; i < 4; ++i)
            if (i > k) T[i][k] = make_double2(0.0, 0.0);
    }

    // Cholesky (upper R): G = R^H R
    double2 R[4][4];
    #pragma unroll
    for (int k = 0; k < 4; ++k) {
        double dk = G4[k][k].x;
        #pragma unroll
        for (int i = 0; i < 4; ++i)
            if (i < k) dk -= R[i][k].x*R[i][k].x + R[i][k].y*R[i][k].y;
        if (dk < 1e-30) dk = 1e-30;
        double rkk = sqrt(dk);
        R[k][k] = make_double2(rkk, 0.0);
        #pragma unroll
        for (int j = 0; j < 4; ++j) if (j > k) {
            double2 acc = G4[k][j];
            #pragma unroll
            for (int i = 0; i < 4; ++i)
                if (i < k) acc = d2sub(acc, d2mul(d2conj(R[i][k]), R[i][j]));
            R[k][j] = make_double2(acc.x/rkk, acc.y/rkk);
        }
    }
    // X = R^-1 (upper triangular back-substitution)
    double2 X[4][4];
    #pragma unroll
    for (int j = 0; j < 4; ++j) {
        #pragma unroll
        for (int i = 0; i < 4; ++i) X[i][j] = make_double2(0.0, 0.0);
        X[j][j] = make_double2(1.0 / R[j][j].x, 0.0);
        #pragma unroll
        for (int ii = 0; ii < 3; ++ii) {
            const int i = j - 1 - ii;
            if (i >= 0) {
                double2 acc = make_double2(0.0, 0.0);
                #pragma unroll
                for (int m2 = 0; m2 < 4; ++m2)
                    if (m2 > i && m2 <= j) acc = d2add(acc, d2mul(R[i][m2], X[m2][j]));
                X[i][j] = make_double2(-acc.x / R[i][i].x, -acc.y / R[i][i].x);
            }
        }
    }
    #pragma unroll
    for (int q = 0; q < 4; ++q)
        #pragma unroll
        for (int j = 0; j < 4; ++j)
            Wout[q*4 + j] = make_float2((float)(X[q][j].x * dsgn[j]),
                                        (float)(X[q][j].y * dsgn[j]));
}

// ---------------------------------------------------------------------------
// Flat grid barrier + liveness, SELECTIVE drain: only waves holding S stores
// (tid<128) wait vmcnt(0); everyone drains lgkm. Other waves' in-flight cold
// loads legitimately span the barrier.
// ---------------------------------------------------------------------------
#define NWG 128u
__device__ __forceinline__ bool site_barrier(unsigned int* addr,
                                             unsigned* nzw, int* live_lds, int tid)
{
    asm volatile("s_waitcnt lgkmcnt(0)" ::: "memory");
    if (tid < 128) asm volatile("s_waitcnt vmcnt(0)" ::: "memory"); // S stores acked
    __builtin_amdgcn_s_barrier();
    __builtin_amdgcn_sched_barrier(0);
    if (tid == 0) {
        unsigned add = 1u | ((nzw[0] | nzw[1]) ? 0x10000u : 0u);
        __hip_atomic_fetch_add(addr, add, __ATOMIC_RELAXED, __HIP_MEMORY_SCOPE_AGENT);
        unsigned v;
        for (;;) {
            v = __hip_atomic_load(addr, __ATOMIC_RELAXED, __HIP_MEMORY_SCOPE_AGENT);
            if ((v & 0xffffu) >= NWG) break;
            __builtin_amdgcn_s_sleep(1);
        }
        *live_lds = (int)(v >> 16);
    }
    asm volatile("s_waitcnt lgkmcnt(0)" ::: "memory");
    __builtin_amdgcn_s_barrier();
    __builtin_amdgcn_sched_barrier(0);
    return *live_lds != 0;
}

// 8 batched cache-bypassing dwordx4 S loads + FMA (one block, one wait)
#define LD8X4_FMA(E0, PA, PB)                                                 \
  {                                                                           \
    float4 t0,t1,t2,t3,t4,t5,t6,t7;                                           \
    asm volatile(                                                             \
      "global_load_dwordx4 %0, %8, off sc0 sc1\n\t"                           \
      "global_load_dwordx4 %1, %8, off offset:1024 sc0 sc1\n\t"               \
      "global_load_dwordx4 %2, %8, off offset:2048 sc0 sc1\n\t"               \
      "global_load_dwordx4 %3, %8, off offset:3072 sc0 sc1\n\t"               \
      "global_load_dwordx4 %4, %9, off sc0 sc1\n\t"                           \
      "global_load_dwordx4 %5, %9, off offset:1024 sc0 sc1\n\t"               \
      "global_load_dwordx4 %6, %9, off offset:2048 sc0 sc1\n\t"               \
      "global_load_dwordx4 %7, %9, off offset:3072 sc0 sc1\n\t"               \
      "s_waitcnt vmcnt(0)"                                                    \
      : "=&v"(t0), "=&v"(t1), "=&v"(t2), "=&v"(t3),                           \
        "=&v"(t4), "=&v"(t5), "=&v"(t6), "=&v"(t7)                            \
      : "v"(PA), "v"(PB));                                                    \
    float4 tt[8] = {t0,t1,t2,t3,t4,t5,t6,t7};                                 \
    _Pragma("unroll")                                                         \
    for (int e = 0; e < 8; ++e) {                                             \
        const int b = sub*16 + (E0) + e;                                      \
        float2 slo = make_float2(tt[e].x, tt[e].y);                           \
        float2 shi = make_float2(tt[e].z, tt[e].w);                           \
        float2 c0 = Clds[0][b], c1 = Clds[1][b];                              \
        float2 c2 = Clds[2][b], c3 = Clds[3][b];                              \
        u00 = cfma(slo, c0, u00);  u10 = cfma(shi, c0, u10);                  \
        u01 = cfma(slo, c1, u01);  u11 = cfma(shi, c1, u11);                  \
        u02 = cfma(slo, c2, u02);  u12 = cfma(shi, c2, u12);                  \
        u03 = cfma(slo, c3, u03);  u13 = cfma(shi, c3, u13);                  \
    }                                                                         \
  }

// ---------------------------------------------------------------------------
// The one cooperative kernel. 128 wgs x 576 threads (8 compute waves + 1
// prefetch wave); wg owns output column c (XCD-grouped mapping).
// ---------------------------------------------------------------------------
__global__ __launch_bounds__(576, 3) void scan_kernel(
    const float* __restrict__ a_re,  const float* __restrict__ a_im,
    const float* __restrict__ b0_re, const float* __restrict__ b0_im,
    const float* __restrict__ bm_re, const float* __restrict__ bm_im,
    const float* __restrict__ bl_re, const float* __restrict__ bl_im,
    const int*  __restrict__ tokens, const float2* __restrict__ Wglob,
    float2* SbufA, float2* SbufB,
    unsigned int* cnt, float* out, int out_size)
{
    const int tid = threadIdx.x;
    const int bid = blockIdx.x;
    const int c   = ((bid & 7) << 4) | (bid >> 3);   // same-XCD wgs -> adjacent c
    const int i16 = bid >> 3;                        // slice index within group

    __shared__ float2 Clds[4][128];        //  4 KB
    __shared__ float4 Upart4[8][256];      // 32 KB
    __shared__ float4 U4[256];             //  4 KB
    __shared__ float4 P16_4[16][64];       // 16 KB
    __shared__ float2 Bpre[2][4][128];     //  8 KB
    __shared__ float2 fred[16];
    __shared__ float2 Wlds[16];
    __shared__ float2 MtLds[2][16];
    __shared__ unsigned nzw[2];
    __shared__ int live_lds;

    const int a = tid & 127;
    const int h = tid >> 7;

    float2* Sread = SbufA;
    float2* Swrite = SbufB;
    bool dead = false;
    float warmacc = 0.f;
    float wm0 = 0.f, wm1 = 0.f, wm2 = 0.f, wm3 = 0.f;  // loop-carried warm

    // ---- prologue warm: FULL tiles 0 and 1, per-group slice i16 (32 KB/wg)
    if (tid < 512) {
        const float4* t0r = (const float4*)bm_re + i16*1024;
        const float4* t0i = (const float4*)bm_im + i16*1024;
        #pragma unroll
        for (int k = 0; k < 2; ++k) {
            float4 x0 = t0r[tid + k*512],          y0 = t0i[tid + k*512];
            float4 x1 = t0r[16384 + tid + k*512],  y1 = t0i[16384 + tid + k*512];
            warmacc += x0.x+x0.y+x0.z+x0.w + y0.x+y0.y+y0.z+y0.w
                     + x1.x+x1.y+x1.z+x1.w + y1.x+y1.y+y1.z+y1.w;
        }
    }

    // ---- W from prep_kernel (tiny, L3-hot)
    if (tid < 16) Wlds[tid] = Wglob[tid];
    __syncthreads();

    // ---- M_0, M_1 and Bpre[1] (site 1 C-operands, tile 0)
    if (tid < 32) {
        const int which = tid >> 4, m = tid & 15;
        MtLds[which][m] = m_entry(a_re, a_im, tokens[which], m, Wlds);
    }
    if (tid < 512) {
        Bpre[1][h][a] = make_float2(bm_re[(h*128 + a)*128 + c],
                                    bm_im[(h*128 + a)*128 + c]);
    }
    __syncthreads();

    // ---- site 0: threads tid<128 compute column c of S0 (transposed store)
    if (tid < 128) {
        const int r = a;
        float2 brr[4], bcc[4];
        for (int p = 0; p < 4; ++p) {
            brr[p] = make_float2(b0_re[p*128 + r], b0_im[p*128 + r]);
            bcc[p] = make_float2(b0_re[p*128 + c], b0_im[p*128 + c]);
        }
        float2 acc = make_float2(0.f, 0.f);
        for (int p = 0; p < 4; ++p) {
            float2 tp = make_float2(0.f, 0.f);
            for (int q = 0; q < 4; ++q) tp = cfma(MtLds[0][p*4 + q], bcc[q], tp);
            acc = cfmac(brr[p], tp, acc);
        }
        st_coh(&SbufA[c*128 + r], acc);
        int nz = (acc.x != 0.f) || (acc.y != 0.f);
        unsigned long long m = __ballot(nz);
        if ((tid & 63) == 0) nzw[tid >> 6] = (m != 0ULL) ? 1u : 0u;
    }

    if (!site_barrier(&cnt[0], nzw, &live_lds, tid)) dead = true;

    if (!dead) {
        for (int t = 1; t <= 510; ++t) {
            const int cur = t & 1, nxt = cur ^ 1;
            const float* br = bm_re + (size_t)(t - 1) * 65536;
            const float* bi = bm_im + (size_t)(t - 1) * 65536;

            // ============ prefetch wave: gather + M + warm-touch ==========
            float2 bp[8];
            float2 macc = make_float2(0.f, 0.f);
            int j = 0;
            if (tid >= 512) {
                j = tid - 512;                         // 0..63
                // consume LAST site's warm touches (had a full site of slack)
                warmacc += wm0 + wm1 + wm2 + wm3;
                // (a) Bpre gather for site t+1 from tile t (L2-warm)
                if (t < 510) {
                    const float* br2 = bm_re + (size_t)t * 65536;
                    const float* bi2 = bm_im + (size_t)t * 65536;
                    #pragma unroll
                    for (int e = 0; e < 8; ++e) {
                        const int idx = j + e*64, q = idx >> 7, a2i = idx & 127;
                        bp[e] = make_float2(br2[(q*128 + a2i)*128 + c],
                                            bi2[(q*128 + a2i)*128 + c]);
                    }
                }
                // (b) M_{t+1} (L2-hot A table)
                if (j < 16) macc = m_entry(a_re, a_im, tokens[t+1], j, Wlds);
                // (c) line-touch warm of tile t+1, slice i16 (1 ld / 128B line)
                if (t < 509) {
                    const float* wr = bm_re + (size_t)(t+1)*65536 + i16*4096;
                    const float* wi = bm_im + (size_t)(t+1)*65536 + i16*4096;
                    wm0 = wr[j*32];  wm1 = wr[2048 + j*32];
                    wm2 = wi[j*32];  wm3 = wi[2048 + j*32];
                } else { wm0 = wm1 = wm2 = wm3 = 0.f; }
            }

            // ================= compute waves (tid < 512) ==================
            // ---- C[p=h][a] from LDS Bpre + LDS M row (no global loads)
            if (tid < 512) {
                float2 acc = make_float2(0.f, 0.f);
                #pragma unroll
                for (int q = 0; q < 4; ++q)
                    acc = cfma(MtLds[cur][h*4 + q], Bpre[cur][q][a], acc);
                Clds[h][a] = acc;
            }
            lds_barrier();

            // ---- U-step: thread sub=tid>>6 (b-block), a2=tid&63 (a-pair);
            //      two asm blocks of 8 dwordx4 bypass loads (32 VGPRs live).
            if (tid < 512) {
                const int sub = tid >> 6, a2 = tid & 63;
                float2 u00 = make_float2(0,0), u01 = u00, u02 = u00, u03 = u00;
                float2 u10 = u00, u11 = u00, u12 = u00, u13 = u00;
                const float2* _b0 = Sread + (sub*16)*128 + 2*a2;
                const float2* _b1 = _b0 + 512;
                const float2* _b2 = _b0 + 1024;
                const float2* _b3 = _b0 + 1536;
                LD8X4_FMA(0, _b0, _b1)
                LD8X4_FMA(8, _b2, _b3)
                Upart4[sub][0*64 + a2] = make_float4(u00.x,u00.y,u10.x,u10.y);
                Upart4[sub][1*64 + a2] = make_float4(u01.x,u01.y,u11.x,u11.y);
                Upart4[sub][2*64 + a2] = make_float4(u02.x,u02.y,u12.x,u12.y);
                Upart4[sub][3*64 + a2] = make_float4(u03.x,u03.y,u13.x,u13.y);
            }
            lds_barrier();
            if (tid < 256) {
                float4 s = Upart4[0][tid];
                #pragma unroll
                for (int w = 1; w < 8; ++w) {
                    float4 x = Upart4[w][tid];
                    s.x += x.x; s.y += x.y; s.z += x.z; s.w += x.w;
                }
                U4[tid] = s;
            }
            lds_barrier();

            // ---- out-step: thread pg=tid>>5 (pa-block), r4=tid&31 (r-quad);
            //      float4 loads (L2-hit after full-tile warm), unroll pairs.
            if (tid < 512) {
                const int pg = tid >> 5, r4 = tid & 31;
                const int p = pg >> 2, abase = (pg & 3) * 32;
                const int pabase = pg * 32;
                const float4* br4 = (const float4*)br;
                const float4* bi4 = (const float4*)bi;
                float2 o0 = make_float2(0,0), o1 = o0, o2 = o0, o3 = o0;
                #pragma unroll 4
                for (int k = 0; k < 32; k += 2) {
                    float4 u2 = U4[p*64 + ((abase + k) >> 1)];
                    float2 Ua = make_float2(u2.x, u2.y);
                    float2 Ub = make_float2(u2.z, u2.w);
                    float4 ra = br4[(pabase + k)*32 + r4];
                    float4 ia = bi4[(pabase + k)*32 + r4];
                    float4 rb = br4[(pabase + k + 1)*32 + r4];
                    float4 ib = bi4[(pabase + k + 1)*32 + r4];
                    o0 = cfmac(make_float2(ra.x, ia.x), Ua, o0);
                    o1 = cfmac(make_float2(ra.y, ia.y), Ua, o1);
                    o2 = cfmac(make_float2(ra.z, ia.z), Ua, o2);
                    o3 = cfmac(make_float2(ra.w, ia.w), Ua, o3);
                    o0 = cfmac(make_float2(rb.x, ib.x), Ub, o0);
                    o1 = cfmac(make_float2(rb.y, ib.y), Ub, o1);
                    o2 = cfmac(make_float2(rb.z, ib.z), Ub, o2);
                    o3 = cfmac(make_float2(rb.w, ib.w), Ub, o3);
                }
                // staggered: 16B/lane consecutive -> conflict-free
                P16_4[pg][r4]      = make_float4(o0.x,o0.y,o1.x,o1.y);
                P16_4[pg][32 + r4] = make_float4(o2.x,o2.y,o3.x,o3.y);
            }
            lds_barrier();
            if (tid < 128) {
                const int r = a;
                const int m = r & 3, q = r >> 2;
                const int pidx = (m < 2) ? (2*q + m) : (64 + 2*q + (m - 2));
                const float2* Prow = (const float2*)(&P16_4[0][0]);
                float2 fin = make_float2(0,0);
                #pragma unroll
                for (int w = 0; w < 16; ++w) {
                    float2 x = Prow[w*128 + pidx];
                    fin.x += x.x; fin.y += x.y;
                }
                st_coh(&Swrite[c * 128 + r], fin);          // write-through
                int nz = (fin.x != 0.f) || (fin.y != 0.f);
                unsigned long long m2 = __ballot(nz);
                if ((tid & 63) == 0) nzw[tid >> 6] = (m2 != 0ULL) ? 1u : 0u;
            }

            // ============ prefetch wave: COMMIT (bp oldest in FIFO) =======
            if (tid >= 512) {
                if (t < 510) {
                    #pragma unroll
                    for (int e = 0; e < 8; ++e) {
                        const int idx = j + e*64, q = idx >> 7, a2i = idx & 127;
                        Bpre[nxt][q][a2i] = bp[e];
                    }
                }
                if (j < 16) MtLds[nxt][j] = macc;
            }

            if (!site_barrier(&cnt[t], nzw, &live_lds, tid)) { dead = true; break; }
            float2* tmp = Sread; Sread = Swrite; Swrite = tmp;
        }
    }
    warmacc += wm0 + wm1 + wm2 + wm3;          // consume final warm touches

    if (out_size < 0) out[2] = warmacc;        // never true: keeps warm loads

    if (dead) {
        if (bid == 0 && tid == 0) {
            out[0] = 0.f;
            if (out_size > 1) out[1] = 0.f;
        }
        return;
    }
    if (bid != 0) return;

    // ---- final site: Bl (4,128,1), M_511 = MtLds[1]; Sread = S(510) transposed
    if (tid < 512) {   // t1[q=h][a] = sum_b S[a,b] * Bl[q,b]
        float2 acc = make_float2(0,0);
        for (int b = 0; b < 128; ++b) {
            float2 s = ld_coh(&Sread[b * 128 + a]);
            float2 bl = make_float2(bl_re[h*128 + b], bl_im[h*128 + b]);
            acc = cfma(s, bl, acc);
        }
        Clds[h][a] = acc;
    }
    __syncthreads();
    float2 tot = make_float2(0,0);
    if (tid < 512) {
        float2 tp = make_float2(0,0);
        for (int q = 0; q < 4; ++q) tp = cfma(MtLds[1][h*4 + q], Clds[q][a], tp);
        float2 blv = make_float2(bl_re[h*128 + a], bl_im[h*128 + a]);
        tot = cfmac(blv, tp, make_float2(0,0));
    }
    for (int off = 32; off; off >>= 1) {
        tot.x += __shfl_down(tot.x, off, 64);
        tot.y += __shfl_down(tot.y, off, 64);
    }
    if ((tid & 63) == 0) fred[tid >> 6] = tot;
    __syncthreads();
    if (tid == 0) {
        float2 s = make_float2(0,0);
        for (int w = 0; w < 9; ++w) { s.x += fred[w].x; s.y += fred[w].y; }
        out[0] = s.x;
        if (out_size > 1) out[1] = s.y;
    }
}

// ---------------------------------------------------------------------------
extern "C" void kernel_launch(void* const* d_in, const int* in_sizes, int n_in,
                              void* d_out, int out_size, void* d_ws, size_t ws_size,
                              hipStream_t stream)
{
    const float* a_re  = (const float*)d_in[0];
    const float* a_im  = (const float*)d_in[1];
    const float* b0_re = (const float*)d_in[2];
    const float* b0_im = (const float*)d_in[3];
    const float* bm_re = (const float*)d_in[4];
    const float* bm_im = (const float*)d_in[5];
    const float* bl_re = (const float*)d_in[6];
    const float* bl_im = (const float*)d_in[7];
    const int*  tokens = (const int*)d_in[8];

    char* ws = (char*)d_ws;
    float2* S0   = (float2*)(ws + 196608);            // 131072 B
    float2* S1b  = (float2*)(ws + 327680);            // 131072 B
    unsigned int* cnt = (unsigned int*)(ws + 458752); // 2048 B
    float2* W    = (float2*)(ws + 460800);            // 128 B

    prep_kernel<<<dim3(1), dim3(512), 0, stream>>>(a_re, a_im, W, cnt);

    float* outf = (float*)d_out;
    int osz = out_size;
    void* args[] = {
        (void*)&a_re, (void*)&a_im, (void*)&b0_re, (void*)&b0_im,
        (void*)&bm_re, (void*)&bm_im, (void*)&bl_re, (void*)&bl_im,
        (void*)&tokens, (void*)&W,
        (void*)&S0, (void*)&S1b, (void*)&cnt, (void*)&outf, (void*)&osz
    };
    hipLaunchCooperativeKernel((const void*)scan_kernel, dim3(128), dim3(576),
                               args, 0, stream);
}